// Round 6
// baseline (538.843 us; speedup 1.0000x reference)
//
#include <hip/hip_runtime.h>

typedef __attribute__((ext_vector_type(8))) short bf16x8;
typedef __attribute__((ext_vector_type(8))) unsigned short ushort8;
typedef __attribute__((ext_vector_type(4))) unsigned short ushort4v;
typedef __attribute__((ext_vector_type(4))) float f32x4;
typedef __attribute__((ext_vector_type(8))) _Float16 f16x8;

__device__ inline unsigned short f2bf(float f){
  unsigned u = __builtin_bit_cast(unsigned, f);
  return (unsigned short)((u + 0x7fffu + ((u>>16)&1u)) >> 16);
}
__device__ inline float bf2f(unsigned short h){
  return __builtin_bit_cast(float, (unsigned)h << 16);
}
__device__ inline unsigned short f2h(float f){
  return __builtin_bit_cast(unsigned short, (_Float16)f);
}
__device__ inline float h2f(unsigned short u){
  return (float)__builtin_bit_cast(_Float16, u);
}

__device__ inline void gll16(const void* g, void* l){
  __builtin_amdgcn_global_load_lds((const __attribute__((address_space(1))) void*)g,
                                   (__attribute__((address_space(3))) void*)l, 16, 0, 0);
}

// ---------------- LayerNorm: x (f32) -> x_norm bf16 into A3[:, 0:256] (row stride 512)
__global__ __launch_bounds__(256) void k_ln(const float* __restrict__ x,
                                            const float* __restrict__ g,
                                            unsigned short* __restrict__ A3){
  int r = blockIdx.x, c = threadIdx.x;
  float v = x[(size_t)r*256 + c];
  float s = v, s2 = v*v;
  #pragma unroll
  for (int m=32; m>=1; m>>=1){ s += __shfl_xor(s, m, 64); s2 += __shfl_xor(s2, m, 64); }
  __shared__ float rs[4], rs2[4];
  int wid = c>>6, lane = c&63;
  if (lane==0){ rs[wid]=s; rs2[wid]=s2; }
  __syncthreads();
  float ts  = rs[0]+rs[1]+rs[2]+rs[3];
  float ts2 = rs2[0]+rs2[1]+rs2[2]+rs2[3];
  float mu  = ts*(1.f/256.f);
  float var = ts2*(1.f/256.f) - mu*mu;
  float xn = (v-mu)*rsqrtf(var + 1e-6f)*g[c];
  A3[(size_t)r*512 + c] = f2bf(xn);
}

// ---------------- column means of x_norm per image
__global__ __launch_bounds__(256) void k_cm1(const unsigned short* __restrict__ A3,
                                             float* __restrict__ psum){
  int blk = blockIdx.x;
  int c = threadIdx.x;
  const unsigned short* base = A3 + (size_t)blk*256*512;
  float s = 0.f;
  for (int p=0;p<256;p++) s += bf2f(base[(size_t)p*512 + c]);
  psum[blk*256 + c] = s;
}
__global__ __launch_bounds__(256) void k_cm2(const float* __restrict__ psum,
                                             float* __restrict__ m){
  int b = blockIdx.x, c = threadIdx.x;
  float s = 0.f;
  for (int ch=0; ch<64; ch++) s += psum[(b*64+ch)*256 + c];
  m[b*256 + c] = s*(1.f/16384.f);
}

// ---------------- weight transposes to bf16 (Bt layout [N][K]) for the two GEMMs
__global__ __launch_bounds__(256) void k_prep_nt(const float* __restrict__ W,
                                                 unsigned short* __restrict__ WT, int K){
  int idx = blockIdx.x*256 + threadIdx.x;
  int j = idx / K, k = idx - j*K;
  WT[idx] = f2bf(W[(size_t)k*256 + j]);
}

// geo weights -> FP16 in panel layout [10][8 k32][4 q][256 n][8 e]
__global__ __launch_bounds__(256) void k_prep_geoT(const float* __restrict__ wl,
                                                   const float* __restrict__ wg,
                                                   unsigned short* __restrict__ WT){
  int idx = blockIdx.x*256 + threadIdx.x;     // over 10*65536, output-linear
  int e = idx & 7, n = (idx>>3)&255, q = (idx>>11)&3, k32 = (idx>>13)&7, sg = idx>>16;
  int k = k32*32 + q*8 + e;
  int j = n;
  float v;
  if (sg < 8){
    int si = sg >> 1, s = 1 << si;
    bool neg = sg & 1;
    int krow = neg ? ((k + s) & 255) : k;
    float wi = wl[(size_t)((2*si)*256 + krow)*256 + j];
    float ww = wl[(size_t)((2*si+1)*256 + krow)*256 + j];
    v = neg ? (wi - ww) : (wi + ww);
  } else {
    v = -2.f * wg[(size_t)((sg-8)*2*256 + k)*256 + j];
  }
  WT[idx] = f2h(v);
}

// W_eff (fp16) in layout [b][8 k32][4 q][256 n=j][8 e]
__global__ __launch_bounds__(256) void k_prep_weff(const float* __restrict__ wg,
                                                   const float* __restrict__ m,
                                                   unsigned short* __restrict__ WT){
  int b = blockIdx.x >> 8, c = blockIdx.x & 255, j = threadIdx.x;
  float acc = 0.f;
  #pragma unroll
  for (int si=0; si<2; ++si){
    int s = si+1;
    int cm = (c - s) & 255, cp = (c + s) & 255;
    float wi_c  = wg[(size_t)((2*si)*256 + c)*256 + j];
    float ww_c  = wg[(size_t)((2*si+1)*256 + c)*256 + j];
    float wi_cp = wg[(size_t)((2*si)*256 + cp)*256 + j];
    float ww_cp = wg[(size_t)((2*si+1)*256 + cp)*256 + j];
    acc += m[b*256+cm]*(wi_c+ww_c) + m[b*256+cp]*(wi_cp-ww_cp);
  }
  size_t addr = (size_t)b*65536 + (size_t)(c>>5)*8192 + (size_t)((c>>3)&3)*2048
              + (size_t)j*8 + (c&7);
  WT[addr] = f2h(acc);
}

// ---------------- fused depthwise 3x3 + 3x3 + BN + SiLU - z_det
__global__ __launch_bounds__(256) void k_dwf(const unsigned short* __restrict__ A3,
                                             const float* __restrict__ w1g,
                                             const float* __restrict__ w2g,
                                             const float* __restrict__ bg,
                                             const float* __restrict__ bm_,
                                             const float* __restrict__ bv,
                                             const unsigned short* __restrict__ zdet,
                                             unsigned short* __restrict__ zcx){
  __shared__ unsigned short t0[12800];   // [20][20][32] bf16
  __shared__ unsigned short t1[10368];   // [18][18][32] fp16
  int t = blockIdx.x;
  int img = t >> 6, ty = (t>>3)&7, tx = t&7;
  int c0 = blockIdx.y*32;
  int tid = threadIdx.x;
  int ch = tid & 31;
  int c = c0 + ch;
  for (int v = tid; v < 3200; v += 256){
    int py = v / 160, rem = v - py*160;
    int px = rem >> 3, ch4 = (rem & 7)*4;
    int gpy = ty*16 - 2 + py, gpx = tx*16 - 2 + px;
    ushort4v val = {0,0,0,0};
    if ((unsigned)gpy < 128u && (unsigned)gpx < 128u){
      size_t gp = (size_t)(img*16384 + gpy*128 + gpx);
      val = *(const ushort4v*)&A3[gp*512 + c0 + ch4];
    }
    *(ushort4v*)&t0[(py*20+px)*32 + ch4] = val;
  }
  float w1[9], w2[9];
  #pragma unroll
  for (int k=0;k<9;k++){ w1[k] = w1g[k*256 + c]; w2[k] = w2g[k*256 + c]; }
  __syncthreads();
  for (int p = tid>>5; p < 324; p += 8){
    int py = p / 18, px = p - py*18;
    int gpy = ty*16 - 1 + py, gpx = tx*16 - 1 + px;
    float acc = 0.f;
    #pragma unroll
    for (int dy=0; dy<3; ++dy)
      #pragma unroll
      for (int dx=0; dx<3; ++dx)
        acc += bf2f(t0[((py+dy)*20 + px+dx)*32 + ch]) * w1[dy*3+dx];
    bool valid = ((unsigned)gpy < 128u) && ((unsigned)gpx < 128u);
    t1[p*32 + ch] = valid ? f2h(acc) : (unsigned short)0;
  }
  __syncthreads();
  float bmv = bm_[c];
  float rsbg = rsqrtf(bv[c] + 1e-3f) * bg[c];
  for (int p = tid>>5; p < 256; p += 8){
    int py = p >> 4, px = p & 15;
    float acc = 0.f;
    #pragma unroll
    for (int dy=0; dy<3; ++dy)
      #pragma unroll
      for (int dx=0; dx<3; ++dx)
        acc += h2f(t1[((py+dy)*18 + px+dx)*32 + ch]) * w2[dy*3+dx];
    float tv = (acc - bmv) * rsbg;
    float sv = tv / (1.f + __expf(-tv));
    size_t gp = (size_t)(img*16384 + (ty*16+py)*128 + tx*16+px);
    float z = sv - h2f(zdet[gp*256 + c]);
    zcx[gp*256 + c] = f2h(z);
  }
}

// ---------------- generic MFMA GEMM: C = A[M,K] * (Bt[N,K])^T, 128x128 tile, BK=64
template<int EPI>
__global__ __launch_bounds__(256) void k_gemm(const unsigned short* __restrict__ A, int lda,
                                              const unsigned short* __restrict__ Bt, int K,
                                              unsigned short* __restrict__ outh,
                                              const float* __restrict__ xin,
                                              const unsigned short* __restrict__ A3,
                                              const float* __restrict__ gls,
                                              float* __restrict__ out){
  __shared__ unsigned short As[128*64];
  __shared__ unsigned short Bs[128*64];
  const int tid=threadIdx.x, lane=tid&63, wid=tid>>6;
  const int bm = blockIdx.x*128, bn = blockIdx.y*128;
  const int wr = wid>>1, wc = wid&1;
  f32x4 acc[4][4] = {};
  const int nk = K>>6;
  const int srow = lane>>3;
  const int skc  = ((lane&7) ^ srow) * 8;
  for (int t=0; t<nk; ++t){
    int k0 = t*64;
    #pragma unroll
    for (int i=0;i<4;i++){
      int q = wid*4 + i;
      int row = q*8 + srow;
      gll16(A  + (size_t)(bm+row)*lda + k0 + skc, &As[q*512]);
      gll16(Bt + (size_t)(bn+row)*K   + k0 + skc, &Bs[q*512]);
    }
    __syncthreads();
    #pragma unroll
    for (int kk=0; kk<2; ++kk){
      bf16x8 af[4], bfr[4];
      #pragma unroll
      for (int i=0;i<4;i++){
        int rl = wr*64 + i*16 + (lane&15);
        int kc = (kk*32 + (lane>>4)*8) ^ ((rl&7)*8);
        af[i]  = *(const bf16x8*)&As[rl*64 + kc];
        int cl = wc*64 + i*16 + (lane&15);
        int kcb = (kk*32 + (lane>>4)*8) ^ ((cl&7)*8);
        bfr[i] = *(const bf16x8*)&Bs[cl*64 + kcb];
      }
      #pragma unroll
      for (int i=0;i<4;i++)
        #pragma unroll
        for (int j=0;j<4;j++)
          acc[i][j] = __builtin_amdgcn_mfma_f32_16x16x32_bf16(af[i], bfr[j], acc[i][j], 0,0,0);
    }
    __syncthreads();
  }
  #pragma unroll
  for (int i=0;i<4;i++)
    #pragma unroll
    for (int j=0;j<4;j++)
      #pragma unroll
      for (int r=0;r<4;r++){
        int row = bm + wr*64 + i*16 + (lane>>4)*4 + r;
        int col = bn + wc*64 + j*16 + (lane&15);
        float v = acc[i][j][r];
        if constexpr (EPI==0){
          outh[(size_t)row*256 + col] = f2h(v);   // z_det in FP16
        } else {
          float alpha = 1.f/(1.f+__expf(-v));
          float xnv = bf2f(A3[(size_t)row*512 + col]);
          float gfv = bf2f(A3[(size_t)row*512 + 256 + col]);
          float sl = xnv/(1.f+__expf(-xnv));
          out[(size_t)row*256 + col] = xin[(size_t)row*256 + col] + (sl + alpha*gfv)*gls[col];
        }
      }
}

// ---------------- fused geo GEMM v6: producer/consumer wave specialization.
// Block = 9 waves: wave 8 stages 16KB weight panels via global_load_lds
// (ring-4, stage-3-ahead, vmcnt(32) pacing); waves 0-7 (2 row-halves x 4
// col-quarters, 64x64 tiles) consume via conflict-free ds_read_b128 and carry
// ONLY operand loads in their vmcnt FIFO (double-banked regs, issued at SEG1,
// used 10 steps later -> no forced drains). Raw s_barrier (no vmcnt drain).
template<int S>
__device__ __attribute__((always_inline)) ushort8 shsel(ushort8 hi, ushort8 lo){
  ushort8 r;
  if constexpr (S==0) return hi;
  #pragma unroll
  for (int e=0;e<8;e++) r[e] = (e<S) ? lo[8-S+e] : hi[e-S];
  return r;
}

template<int SEG>
__device__ __attribute__((always_inline)) f16x8 gen2(ushort8 zdh, ushort8 zdl,
      ushort8 zch, ushort8 zcl, ushort8 zcu){
  if constexpr (SEG==10) return __builtin_bit_cast(f16x8, zdh);
  ushort8 sel;
  if constexpr      (SEG==0) sel = shsel<1>(zch, zcl);
  else if constexpr (SEG==1) sel = shsel<7>(zcu, zch);
  else if constexpr (SEG==2) sel = shsel<2>(zch, zcl);
  else if constexpr (SEG==3) sel = shsel<6>(zcu, zch);
  else if constexpr (SEG==4) sel = shsel<4>(zch, zcl);
  else if constexpr (SEG==5) sel = shsel<4>(zcu, zch);
  else if constexpr (SEG==6) sel = zcl;
  else if constexpr (SEG==7) sel = zcu;
  else if constexpr (SEG==8) sel = shsel<1>(zdh, zdl);
  else                       sel = shsel<2>(zdh, zdl);
  return __builtin_bit_cast(f16x8, zdh) * __builtin_bit_cast(f16x8, sel);
}

__global__ __launch_bounds__(576) void k_geo(const unsigned short* __restrict__ zd,
                                             const unsigned short* __restrict__ zc,
                                             const unsigned short* __restrict__ WT_all,
                                             const unsigned short* __restrict__ WeffT,
                                             unsigned short* __restrict__ A3){
  __shared__ unsigned short Bs[4][8192];     // ring-4 x 16KB panels [q][n][8]
  const int tid = threadIdx.x, lane = tid&63, wid = tid>>6;
  const int bm = blockIdx.x*128;
  const int img = blockIdx.x >> 7;           // 128 blocks per image
  const unsigned short* weff = WeffT + (size_t)img*65536;

  if (wid == 8){
    // ---- producer wave ----
    unsigned short* lds0 = &Bs[0][0];
    // prologue: stage panels for steps 0,1,2 (segs 0,1,2 of k32=0)
    #pragma unroll
    for (int s=0; s<3; ++s){
      const unsigned short* src = WT_all + (size_t)s*65536 + lane*8;
      unsigned short* dst = lds0 + s*8192 + lane*8;
      #pragma unroll
      for (int g=0; g<16; ++g) gll16(src + g*512, dst + g*512);
    }
    for (int t=0; t<88; ++t){
      asm volatile("s_waitcnt vmcnt(32)" ::: "memory");
      __builtin_amdgcn_s_barrier();
      int st = t+3; if (st > 87) st = 87;
      int k32 = (st*373)>>12;                // st/11 exact for st in [0,90]
      int seg = st - k32*11;
      const unsigned short* src = ((seg<10) ? (WT_all + (size_t)seg*65536) : weff)
                                  + (size_t)k32*8192 + lane*8;
      unsigned short* dst = lds0 + ((t+3)&3)*8192 + lane*8;
      #pragma unroll
      for (int g=0; g<16; ++g) gll16(src + g*512, dst + g*512);
    }
    return;
  }

  // ---- consumer waves ----
  const int cq = wid & 3, rh = wid >> 2;
  f32x4 acc[4][4] = {};                      // [rg][fj]
  const int boff = (lane>>4)*2048 + (cq*64 + (lane&15))*8;   // halfs, +fj*128
  const unsigned short* ldsF = &Bs[0][0];
  int curh = 0;                              // ring offset in halfs

  const int mrow = bm + rh*64 + (lane&15);
  const unsigned short* zrow[4];
  const unsigned short* crow[4];
  #pragma unroll
  for (int rg=0; rg<4; ++rg){
    zrow[rg] = zd + (size_t)(mrow + rg*16)*256;
    crow[rg] = zc + (size_t)(mrow + rg*16)*256;
  }

  ushort8 zdhA[4], zdlA[4], zchA[4], zclA[4], zcuA[4];
  ushort8 zdhB[4], zdlB[4], zchB[4], zclB[4], zcuB[4];

#define LOAD_OPS(BK, K32) { \
    int kc_ = (K32)*32 + (lane>>4)*8; \
    int kl_ = (kc_-8)&255, ku_ = (kc_+8)&255; \
    _Pragma("unroll") \
    for (int rg=0; rg<4; ++rg){ \
      zdh##BK[rg] = *(const ushort8*)(zrow[rg] + kc_); \
      zdl##BK[rg] = *(const ushort8*)(zrow[rg] + kl_); \
      zch##BK[rg] = *(const ushort8*)(crow[rg] + kc_); \
      zcl##BK[rg] = *(const ushort8*)(crow[rg] + kl_); \
      zcu##BK[rg] = *(const ushort8*)(crow[rg] + ku_); \
    } }

#define CSTEP(SEG, BK, PF) { \
    __builtin_amdgcn_s_barrier(); \
    __builtin_amdgcn_sched_barrier(0); \
    PF \
    f16x8 bfr[4]; \
    const unsigned short* bp = ldsF + curh + boff; \
    bfr[0] = *(const f16x8*)(bp); \
    bfr[1] = *(const f16x8*)(bp + 128); \
    bfr[2] = *(const f16x8*)(bp + 256); \
    bfr[3] = *(const f16x8*)(bp + 384); \
    f16x8 af[4]; \
    _Pragma("unroll") \
    for (int rg=0; rg<4; ++rg) \
      af[rg] = gen2<(SEG)>(zdh##BK[rg],zdl##BK[rg],zch##BK[rg],zcl##BK[rg],zcu##BK[rg]); \
    __builtin_amdgcn_s_setprio(1); \
    _Pragma("unroll") \
    for (int fj=0; fj<4; ++fj){ \
      _Pragma("unroll") \
      for (int rg=0; rg<4; ++rg) \
        acc[rg][fj] = __builtin_amdgcn_mfma_f32_16x16x32_f16(af[rg], bfr[fj], acc[rg][fj], 0,0,0); \
    } \
    __builtin_amdgcn_s_setprio(0); \
    curh = (curh + 8192) & 32767; \
  }

#define ROUND(K32, BK, NBK) \
    CSTEP(0, BK, ) \
    CSTEP(1, BK, LOAD_OPS(NBK, ((K32)<7 ? (K32)+1 : 7))) \
    CSTEP(2, BK, ) CSTEP(3, BK, ) CSTEP(4, BK, ) CSTEP(5, BK, ) \
    CSTEP(6, BK, ) CSTEP(7, BK, ) CSTEP(8, BK, ) CSTEP(9, BK, ) \
    CSTEP(10, BK, )

  LOAD_OPS(A, 0)
  ROUND(0, A, B)
  ROUND(1, B, A)
  ROUND(2, A, B)
  ROUND(3, B, A)
  ROUND(4, A, B)
  ROUND(5, B, A)
  ROUND(6, A, B)
  ROUND(7, B, A)
#undef ROUND
#undef CSTEP
#undef LOAD_OPS

  #pragma unroll
  for (int rg=0; rg<4; ++rg)
    #pragma unroll
    for (int fj=0; fj<4; ++fj)
      #pragma unroll
      for (int r=0; r<4; ++r){
        int row = bm + rh*64 + rg*16 + (lane>>4)*4 + r;
        int col = cq*64 + fj*16 + (lane&15);
        A3[(size_t)row*512 + 256 + col] = f2bf(acc[rg][fj][r]);
      }
}

extern "C" void kernel_launch(void* const* d_in, const int* in_sizes, int n_in,
                              void* d_out, int out_size, void* d_ws, size_t ws_size,
                              hipStream_t stream){
  (void)in_sizes; (void)n_in; (void)out_size; (void)ws_size;
  const float* x    = (const float*)d_in[0];
  const float* lng  = (const float*)d_in[1];
  const float* wdet = (const float*)d_in[2];
  const float* dw1  = (const float*)d_in[3];
  const float* dw2  = (const float*)d_in[4];
  const float* bng  = (const float*)d_in[5];
  const float* bnm  = (const float*)d_in[6];
  const float* bnv  = (const float*)d_in[7];
  const float* wloc = (const float*)d_in[8];
  const float* wglo = (const float*)d_in[9];
  const float* wgat = (const float*)d_in[10];
  const float* gls  = (const float*)d_in[11];
  float* out = (float*)d_out;
  char* ws = (char*)d_ws;

  unsigned short* A3     = (unsigned short*)(ws);                 // 64 MB [65536][512] bf16
  unsigned short* ZDET   = (unsigned short*)(ws + 67108864);      // 32 MB fp16
  unsigned short* ZCX    = (unsigned short*)(ws + 134217728);     // 32 MB fp16
  unsigned short* WTALL  = (unsigned short*)(ws + 167772160);     // 1.25 MB fp16 [10][8][4][256][8]
  unsigned short* WEFFT  = (unsigned short*)(ws + 169213952);     // 0.5 MB fp16 [4][8][4][256][8]
  unsigned short* WDETT  = (unsigned short*)(ws + 169738240);     // 128 KB bf16
  unsigned short* WGATET = (unsigned short*)(ws + 169869312);     // 256 KB bf16
  float* PSUM  = (float*)(ws + 170131456);                        // 256 KB
  float* MMEAN = (float*)(ws + 170393600);                        // 4 KB

  k_ln<<<65536, 256, 0, stream>>>(x, lng, A3);
  k_cm1<<<256, 256, 0, stream>>>(A3, PSUM);
  k_cm2<<<4, 256, 0, stream>>>(PSUM, MMEAN);
  k_prep_nt<<<256, 256, 0, stream>>>(wdet, WDETT, 256);
  k_prep_nt<<<512, 256, 0, stream>>>(wgat, WGATET, 512);
  k_prep_geoT<<<2560, 256, 0, stream>>>(wloc, wglo, WTALL);
  k_prep_weff<<<1024, 256, 0, stream>>>(wglo, MMEAN, WEFFT);
  k_gemm<0><<<dim3(512,2), 256, 0, stream>>>(A3, 512, WDETT, 256, ZDET,
                                             nullptr, nullptr, nullptr, nullptr);
  k_dwf<<<dim3(256,8), 256, 0, stream>>>(A3, dw1, dw2, bng, bnm, bnv, ZDET, ZCX);
  k_geo<<<512, 576, 0, stream>>>(ZDET, ZCX, WTALL, WEFFT, A3);
  k_gemm<1><<<dim3(512,2), 256, 0, stream>>>(A3, 512, WGATET, 512, nullptr,
                                             x, A3, gls, out);
}

// Round 7
// 337.379 us; speedup vs baseline: 1.5971x; 1.5971x over previous
//
#include <hip/hip_runtime.h>

typedef __attribute__((ext_vector_type(8))) short bf16x8;
typedef __attribute__((ext_vector_type(8))) unsigned short ushort8;
typedef __attribute__((ext_vector_type(4))) unsigned short ushort4v;
typedef __attribute__((ext_vector_type(4))) float f32x4;
typedef __attribute__((ext_vector_type(4))) float float4v;
typedef __attribute__((ext_vector_type(8))) _Float16 f16x8;

__device__ inline unsigned short f2bf(float f){
  unsigned u = __builtin_bit_cast(unsigned, f);
  return (unsigned short)((u + 0x7fffu + ((u>>16)&1u)) >> 16);
}
__device__ inline float bf2f(unsigned short h){
  return __builtin_bit_cast(float, (unsigned)h << 16);
}
__device__ inline unsigned short f2h(float f){
  return __builtin_bit_cast(unsigned short, (_Float16)f);
}
__device__ inline float h2f(unsigned short u){
  return (float)__builtin_bit_cast(_Float16, u);
}

__device__ inline void gll16(const void* g, void* l){
  __builtin_amdgcn_global_load_lds((const __attribute__((address_space(1))) void*)g,
                                   (__attribute__((address_space(3))) void*)l, 16, 0, 0);
}

// ---------------- LayerNorm: one wave per row, float4 loads
__global__ __launch_bounds__(256) void k_ln(const float* __restrict__ x,
                                            const float* __restrict__ g,
                                            unsigned short* __restrict__ A3){
  int wid = threadIdx.x >> 6, lane = threadIdx.x & 63;
  int row = blockIdx.x*4 + wid;
  float4v v = *(const float4v*)&x[(size_t)row*256 + lane*4];
  float4v gv = *(const float4v*)&g[lane*4];
  float s  = v[0]+v[1]+v[2]+v[3];
  float s2 = v[0]*v[0]+v[1]*v[1]+v[2]*v[2]+v[3]*v[3];
  #pragma unroll
  for (int m=32; m>=1; m>>=1){ s += __shfl_xor(s, m, 64); s2 += __shfl_xor(s2, m, 64); }
  float mu  = s*(1.f/256.f);
  float var = s2*(1.f/256.f) - mu*mu;
  float rst = rsqrtf(var + 1e-6f);
  ushort4v o;
  #pragma unroll
  for (int e=0;e<4;e++) o[e] = f2bf((v[e]-mu)*rst*gv[e]);
  *(ushort4v*)&A3[(size_t)row*512 + lane*4] = o;
}

// ---------------- column means of x_norm per image
__global__ __launch_bounds__(256) void k_cm1(const unsigned short* __restrict__ A3,
                                             float* __restrict__ psum){
  int blk = blockIdx.x;
  int c = threadIdx.x;
  const unsigned short* base = A3 + (size_t)blk*256*512;
  float s = 0.f;
  for (int p=0;p<256;p++) s += bf2f(base[(size_t)p*512 + c]);
  psum[blk*256 + c] = s;
}
__global__ __launch_bounds__(256) void k_cm2(const float* __restrict__ psum,
                                             float* __restrict__ m){
  int b = blockIdx.x, c = threadIdx.x;
  float s = 0.f;
  for (int ch=0; ch<64; ch++) s += psum[(b*64+ch)*256 + c];
  m[b*256 + c] = s*(1.f/16384.f);
}

// ---------------- weight transposes to bf16 (Bt layout [N][K]) for the two GEMMs
__global__ __launch_bounds__(256) void k_prep_nt(const float* __restrict__ W,
                                                 unsigned short* __restrict__ WT, int K){
  int idx = blockIdx.x*256 + threadIdx.x;
  int j = idx / K, k = idx - j*K;
  WT[idx] = f2bf(W[(size_t)k*256 + j]);
}

// geo weights -> FP16 in panel layout [10][8 k32][4 q][256 n][8 e]
__global__ __launch_bounds__(256) void k_prep_geoT(const float* __restrict__ wl,
                                                   const float* __restrict__ wg,
                                                   unsigned short* __restrict__ WT){
  int idx = blockIdx.x*256 + threadIdx.x;     // over 10*65536, output-linear
  int e = idx & 7, n = (idx>>3)&255, q = (idx>>11)&3, k32 = (idx>>13)&7, sg = idx>>16;
  int k = k32*32 + q*8 + e;
  int j = n;
  float v;
  if (sg < 8){
    int si = sg >> 1, s = 1 << si;
    bool neg = sg & 1;
    int krow = neg ? ((k + s) & 255) : k;
    float wi = wl[(size_t)((2*si)*256 + krow)*256 + j];
    float ww = wl[(size_t)((2*si+1)*256 + krow)*256 + j];
    v = neg ? (wi - ww) : (wi + ww);
  } else {
    v = -2.f * wg[(size_t)((sg-8)*2*256 + k)*256 + j];
  }
  WT[idx] = f2h(v);
}

// W_eff (fp16) in layout [b][8 k32][4 q][256 n=j][8 e]
__global__ __launch_bounds__(256) void k_prep_weff(const float* __restrict__ wg,
                                                   const float* __restrict__ m,
                                                   unsigned short* __restrict__ WT){
  int b = blockIdx.x >> 8, c = blockIdx.x & 255, j = threadIdx.x;
  float acc = 0.f;
  #pragma unroll
  for (int si=0; si<2; ++si){
    int s = si+1;
    int cm = (c - s) & 255, cp = (c + s) & 255;
    float wi_c  = wg[(size_t)((2*si)*256 + c)*256 + j];
    float ww_c  = wg[(size_t)((2*si+1)*256 + c)*256 + j];
    float wi_cp = wg[(size_t)((2*si)*256 + cp)*256 + j];
    float ww_cp = wg[(size_t)((2*si+1)*256 + cp)*256 + j];
    acc += m[b*256+cm]*(wi_c+ww_c) + m[b*256+cp]*(wi_cp-ww_cp);
  }
  size_t addr = (size_t)b*65536 + (size_t)(c>>5)*8192 + (size_t)((c>>3)&3)*2048
              + (size_t)j*8 + (c&7);
  WT[addr] = f2h(acc);
}

// ---------------- fused depthwise 3x3 + 3x3 + BN + SiLU - z_det
__global__ __launch_bounds__(256) void k_dwf(const unsigned short* __restrict__ A3,
                                             const float* __restrict__ w1g,
                                             const float* __restrict__ w2g,
                                             const float* __restrict__ bg,
                                             const float* __restrict__ bm_,
                                             const float* __restrict__ bv,
                                             const unsigned short* __restrict__ zdet,
                                             unsigned short* __restrict__ zcx){
  __shared__ unsigned short t0[12800];   // [20][20][32] bf16
  __shared__ unsigned short t1[10368];   // [18][18][32] fp16
  int t = blockIdx.x;
  int img = t >> 6, ty = (t>>3)&7, tx = t&7;
  int c0 = blockIdx.y*32;
  int tid = threadIdx.x;
  int ch = tid & 31;
  int c = c0 + ch;
  for (int v = tid; v < 3200; v += 256){
    int py = v / 160, rem = v - py*160;
    int px = rem >> 3, ch4 = (rem & 7)*4;
    int gpy = ty*16 - 2 + py, gpx = tx*16 - 2 + px;
    ushort4v val = {0,0,0,0};
    if ((unsigned)gpy < 128u && (unsigned)gpx < 128u){
      size_t gp = (size_t)(img*16384 + gpy*128 + gpx);
      val = *(const ushort4v*)&A3[gp*512 + c0 + ch4];
    }
    *(ushort4v*)&t0[(py*20+px)*32 + ch4] = val;
  }
  float w1[9], w2[9];
  #pragma unroll
  for (int k=0;k<9;k++){ w1[k] = w1g[k*256 + c]; w2[k] = w2g[k*256 + c]; }
  __syncthreads();
  for (int p = tid>>5; p < 324; p += 8){
    int py = p / 18, px = p - py*18;
    int gpy = ty*16 - 1 + py, gpx = tx*16 - 1 + px;
    float acc = 0.f;
    #pragma unroll
    for (int dy=0; dy<3; ++dy)
      #pragma unroll
      for (int dx=0; dx<3; ++dx)
        acc += bf2f(t0[((py+dy)*20 + px+dx)*32 + ch]) * w1[dy*3+dx];
    bool valid = ((unsigned)gpy < 128u) && ((unsigned)gpx < 128u);
    t1[p*32 + ch] = valid ? f2h(acc) : (unsigned short)0;
  }
  __syncthreads();
  float bmv = bm_[c];
  float rsbg = rsqrtf(bv[c] + 1e-3f) * bg[c];
  for (int p = tid>>5; p < 256; p += 8){
    int py = p >> 4, px = p & 15;
    float acc = 0.f;
    #pragma unroll
    for (int dy=0; dy<3; ++dy)
      #pragma unroll
      for (int dx=0; dx<3; ++dx)
        acc += h2f(t1[((py+dy)*18 + px+dx)*32 + ch]) * w2[dy*3+dx];
    float tv = (acc - bmv) * rsbg;
    float sv = tv / (1.f + __expf(-tv));
    size_t gp = (size_t)(img*16384 + (ty*16+py)*128 + tx*16+px);
    float z = sv - h2f(zdet[gp*256 + c]);
    zcx[gp*256 + c] = f2h(z);
  }
}

// ---------------- generic MFMA GEMM: C = A[M,K] * (Bt[N,K])^T, 128x128 tile, BK=64
template<int EPI>
__global__ __launch_bounds__(256) void k_gemm(const unsigned short* __restrict__ A, int lda,
                                              const unsigned short* __restrict__ Bt, int K,
                                              unsigned short* __restrict__ outh,
                                              const float* __restrict__ xin,
                                              const unsigned short* __restrict__ A3,
                                              const float* __restrict__ gls,
                                              float* __restrict__ out){
  __shared__ unsigned short As[128*64];
  __shared__ unsigned short Bs[128*64];
  const int tid=threadIdx.x, lane=tid&63, wid=tid>>6;
  const int bm = blockIdx.x*128, bn = blockIdx.y*128;
  const int wr = wid>>1, wc = wid&1;
  f32x4 acc[4][4] = {};
  const int nk = K>>6;
  const int srow = lane>>3;
  const int skc  = ((lane&7) ^ srow) * 8;
  for (int t=0; t<nk; ++t){
    int k0 = t*64;
    #pragma unroll
    for (int i=0;i<4;i++){
      int q = wid*4 + i;
      int row = q*8 + srow;
      gll16(A  + (size_t)(bm+row)*lda + k0 + skc, &As[q*512]);
      gll16(Bt + (size_t)(bn+row)*K   + k0 + skc, &Bs[q*512]);
    }
    __syncthreads();
    #pragma unroll
    for (int kk=0; kk<2; ++kk){
      bf16x8 af[4], bfr[4];
      #pragma unroll
      for (int i=0;i<4;i++){
        int rl = wr*64 + i*16 + (lane&15);
        int kc = (kk*32 + (lane>>4)*8) ^ ((rl&7)*8);
        af[i]  = *(const bf16x8*)&As[rl*64 + kc];
        int cl = wc*64 + i*16 + (lane&15);
        int kcb = (kk*32 + (lane>>4)*8) ^ ((cl&7)*8);
        bfr[i] = *(const bf16x8*)&Bs[cl*64 + kcb];
      }
      #pragma unroll
      for (int i=0;i<4;i++)
        #pragma unroll
        for (int j=0;j<4;j++)
          acc[i][j] = __builtin_amdgcn_mfma_f32_16x16x32_bf16(af[i], bfr[j], acc[i][j], 0,0,0);
    }
    __syncthreads();
  }
  #pragma unroll
  for (int i=0;i<4;i++)
    #pragma unroll
    for (int j=0;j<4;j++)
      #pragma unroll
      for (int r=0;r<4;r++){
        int row = bm + wr*64 + i*16 + (lane>>4)*4 + r;
        int col = bn + wc*64 + j*16 + (lane&15);
        float v = acc[i][j][r];
        if constexpr (EPI==0){
          outh[(size_t)row*256 + col] = f2h(v);   // z_det in FP16
        } else {
          float alpha = 1.f/(1.f+__expf(-v));
          float xnv = bf2f(A3[(size_t)row*512 + col]);
          float gfv = bf2f(A3[(size_t)row*512 + 256 + col]);
          float sl = xnv/(1.f+__expf(-xnv));
          out[(size_t)row*256 + col] = xin[(size_t)row*256 + col] + (sl + alpha*gfv)*gls[col];
        }
      }
}

// ---------------- fused geo GEMM v7: 8 waves, distributed panel staging.
// Wave (t&7) stages panel slot (t+3)&3 (16 x global_load_lds, ring-4).
// Race safety: after staging, a wave issues at most 12 more global loads
// before its end-of-step "s_waitcnt vmcnt(10)", so vmcnt(10)+s_barrier at
// step t proves panel t+3 is resident >=2 barriers before any wave reads it.
// Operands single-banked (R5 schedule): zc reloaded at SEG8, zd at SEG10.
template<int S>
__device__ __attribute__((always_inline)) ushort8 shsel(ushort8 hi, ushort8 lo){
  ushort8 r;
  if constexpr (S==0) return hi;
  #pragma unroll
  for (int e=0;e<8;e++) r[e] = (e<S) ? lo[8-S+e] : hi[e-S];
  return r;
}

template<int SEG>
__device__ __attribute__((always_inline)) f16x8 gen2(ushort8 zdh, ushort8 zdl,
      ushort8 zch, ushort8 zcl, ushort8 zcu){
  if constexpr (SEG==10) return __builtin_bit_cast(f16x8, zdh);
  ushort8 sel;
  if constexpr      (SEG==0) sel = shsel<1>(zch, zcl);
  else if constexpr (SEG==1) sel = shsel<7>(zcu, zch);
  else if constexpr (SEG==2) sel = shsel<2>(zch, zcl);
  else if constexpr (SEG==3) sel = shsel<6>(zcu, zch);
  else if constexpr (SEG==4) sel = shsel<4>(zch, zcl);
  else if constexpr (SEG==5) sel = shsel<4>(zcu, zch);
  else if constexpr (SEG==6) sel = zcl;
  else if constexpr (SEG==7) sel = zcu;
  else if constexpr (SEG==8) sel = shsel<1>(zdh, zdl);
  else                       sel = shsel<2>(zdh, zdl);
  return __builtin_bit_cast(f16x8, zdh) * __builtin_bit_cast(f16x8, sel);
}

__global__ __launch_bounds__(512, 2) void k_geo(const unsigned short* __restrict__ zd,
                                                const unsigned short* __restrict__ zc,
                                                const unsigned short* __restrict__ WT_all,
                                                const unsigned short* __restrict__ WeffT,
                                                unsigned short* __restrict__ A3){
  __shared__ unsigned short Bs[4][8192];     // ring-4 x 16KB panels [q][n][8]
  const int tid = threadIdx.x, lane = tid&63, wid = tid>>6;
  const int bm = blockIdx.x*128;
  const int img = blockIdx.x >> 7;
  const unsigned short* weff = WeffT + (size_t)img*65536;
  const int rh = wid >> 2, cq = wid & 3;     // wave tile: 64 rows x 64 cols
  f32x4 acc[4][4] = {};
  const int boff = (lane>>4)*2048 + (cq*64 + (lane&15))*8;   // halfs

  const int mrow = bm + rh*64 + (lane&15);
  const unsigned short* zrow[4];
  const unsigned short* crow[4];
  #pragma unroll
  for (int rg=0; rg<4; ++rg){
    zrow[rg] = zd + (size_t)(mrow + rg*16)*256;
    crow[rg] = zc + (size_t)(mrow + rg*16)*256;
  }

  ushort8 zdh[4], zdl[4], zch[4], zcl[4], zcu[4];

  // prologue: waves 0-2 stage panels 0,1,2 (segs 0,1,2 of k32=0)
  if (wid < 3){
    const unsigned short* src = WT_all + (size_t)wid*65536 + lane*8;
    unsigned short* dst = &Bs[wid][0];
    #pragma unroll
    for (int gq=0; gq<16; ++gq) gll16(src + gq*512, dst + gq*512);
    asm volatile("s_waitcnt vmcnt(0)" ::: "memory");
  }
  // initial operands (k32 = 0)
  {
    int kc = (lane>>4)*8, kl = (kc-8)&255, ku = (kc+8)&255;
    #pragma unroll
    for (int rg=0; rg<4; ++rg){
      zdh[rg] = *(const ushort8*)(zrow[rg] + kc);
      zdl[rg] = *(const ushort8*)(zrow[rg] + kl);
      zch[rg] = *(const ushort8*)(crow[rg] + kc);
      zcl[rg] = *(const ushort8*)(crow[rg] + kl);
      zcu[rg] = *(const ushort8*)(crow[rg] + ku);
    }
  }
  __builtin_amdgcn_s_barrier();

  int t = 0, cur = 0;

#define CSTEP(SEG) { \
    if (((t & 7) == wid) && (t+3) < 88){ \
      int st = t + 3; \
      int k32s = (st*373) >> 12; \
      int segs = st - k32s*11; \
      const unsigned short* src = ((segs<10) ? (WT_all + (size_t)segs*65536) : weff) \
                                  + (size_t)k32s*8192 + lane*8; \
      unsigned short* dst = &Bs[st & 3][0]; \
      _Pragma("unroll") \
      for (int gq=0; gq<16; ++gq) gll16(src + gq*512, dst + gq*512); \
    } \
    f16x8 bfr[4]; \
    const unsigned short* bp = &Bs[0][0] + cur*8192 + boff; \
    bfr[0] = *(const f16x8*)(bp); \
    bfr[1] = *(const f16x8*)(bp + 128); \
    bfr[2] = *(const f16x8*)(bp + 256); \
    bfr[3] = *(const f16x8*)(bp + 384); \
    if constexpr ((SEG)==8){ \
      int k32n = (k32<7) ? k32+1 : 7; \
      int kc_ = k32n*32 + (lane>>4)*8; \
      int kl_ = (kc_-8)&255, ku_ = (kc_+8)&255; \
      _Pragma("unroll") \
      for (int rg=0; rg<4; ++rg){ \
        zch[rg] = *(const ushort8*)(crow[rg] + kc_); \
        zcl[rg] = *(const ushort8*)(crow[rg] + kl_); \
        zcu[rg] = *(const ushort8*)(crow[rg] + ku_); \
      } \
    } \
    f16x8 af[4]; \
    _Pragma("unroll") \
    for (int rg=0; rg<4; ++rg) \
      af[rg] = gen2<(SEG)>(zdh[rg],zdl[rg],zch[rg],zcl[rg],zcu[rg]); \
    if constexpr ((SEG)==10){ \
      int k32n = (k32<7) ? k32+1 : 7; \
      int kc_ = k32n*32 + (lane>>4)*8; \
      int kl_ = (kc_-8)&255; \
      _Pragma("unroll") \
      for (int rg=0; rg<4; ++rg){ \
        zdh[rg] = *(const ushort8*)(zrow[rg] + kc_); \
        zdl[rg] = *(const ushort8*)(zrow[rg] + kl_); \
      } \
    } \
    __builtin_amdgcn_s_setprio(1); \
    _Pragma("unroll") \
    for (int fj=0; fj<4; ++fj){ \
      _Pragma("unroll") \
      for (int rg=0; rg<4; ++rg) \
        acc[rg][fj] = __builtin_amdgcn_mfma_f32_16x16x32_f16(af[rg], bfr[fj], acc[rg][fj], 0,0,0); \
    } \
    __builtin_amdgcn_s_setprio(0); \
    asm volatile("s_waitcnt vmcnt(10)" ::: "memory"); \
    __builtin_amdgcn_s_barrier(); \
    cur = (cur+1) & 3; \
    ++t; \
  }

  for (int k32=0; k32<8; ++k32){
    CSTEP(0) CSTEP(1) CSTEP(2) CSTEP(3) CSTEP(4) CSTEP(5)
    CSTEP(6) CSTEP(7) CSTEP(8) CSTEP(9) CSTEP(10)
  }
#undef CSTEP

  #pragma unroll
  for (int rg=0; rg<4; ++rg)
    #pragma unroll
    for (int fj=0; fj<4; ++fj)
      #pragma unroll
      for (int r=0; r<4; ++r){
        int row = bm + rh*64 + rg*16 + (lane>>4)*4 + r;
        int col = cq*64 + fj*16 + (lane&15);
        A3[(size_t)row*512 + 256 + col] = f2bf(acc[rg][fj][r]);
      }
}

extern "C" void kernel_launch(void* const* d_in, const int* in_sizes, int n_in,
                              void* d_out, int out_size, void* d_ws, size_t ws_size,
                              hipStream_t stream){
  (void)in_sizes; (void)n_in; (void)out_size; (void)ws_size;
  const float* x    = (const float*)d_in[0];
  const float* lng  = (const float*)d_in[1];
  const float* wdet = (const float*)d_in[2];
  const float* dw1  = (const float*)d_in[3];
  const float* dw2  = (const float*)d_in[4];
  const float* bng  = (const float*)d_in[5];
  const float* bnm  = (const float*)d_in[6];
  const float* bnv  = (const float*)d_in[7];
  const float* wloc = (const float*)d_in[8];
  const float* wglo = (const float*)d_in[9];
  const float* wgat = (const float*)d_in[10];
  const float* gls  = (const float*)d_in[11];
  float* out = (float*)d_out;
  char* ws = (char*)d_ws;

  unsigned short* A3     = (unsigned short*)(ws);                 // 64 MB [65536][512] bf16
  unsigned short* ZDET   = (unsigned short*)(ws + 67108864);      // 32 MB fp16
  unsigned short* ZCX    = (unsigned short*)(ws + 134217728);     // 32 MB fp16
  unsigned short* WTALL  = (unsigned short*)(ws + 167772160);     // 1.25 MB fp16 [10][8][4][256][8]
  unsigned short* WEFFT  = (unsigned short*)(ws + 169213952);     // 0.5 MB fp16 [4][8][4][256][8]
  unsigned short* WDETT  = (unsigned short*)(ws + 169738240);     // 128 KB bf16
  unsigned short* WGATET = (unsigned short*)(ws + 169869312);     // 256 KB bf16
  float* PSUM  = (float*)(ws + 170131456);                        // 256 KB
  float* MMEAN = (float*)(ws + 170393600);                        // 4 KB

  k_ln<<<16384, 256, 0, stream>>>(x, lng, A3);
  k_cm1<<<256, 256, 0, stream>>>(A3, PSUM);
  k_cm2<<<4, 256, 0, stream>>>(PSUM, MMEAN);
  k_prep_nt<<<256, 256, 0, stream>>>(wdet, WDETT, 256);
  k_prep_nt<<<512, 256, 0, stream>>>(wgat, WGATET, 512);
  k_prep_geoT<<<2560, 256, 0, stream>>>(wloc, wglo, WTALL);
  k_prep_weff<<<1024, 256, 0, stream>>>(wglo, MMEAN, WEFFT);
  k_gemm<0><<<dim3(512,2), 256, 0, stream>>>(A3, 512, WDETT, 256, ZDET,
                                             nullptr, nullptr, nullptr, nullptr);
  k_dwf<<<dim3(256,8), 256, 0, stream>>>(A3, dw1, dw2, bng, bnm, bnv, ZDET, ZCX);
  k_geo<<<512, 512, 0, stream>>>(ZDET, ZCX, WTALL, WEFFT, A3);
  k_gemm<1><<<dim3(512,2), 256, 0, stream>>>(A3, 512, WGATET, 512, nullptr,
                                             x, A3, gls, out);
}